// Round 3
// baseline (4936.270 us; speedup 1.0000x reference)
//
#include <hip/hip_runtime.h>

// GCNConv via XCD-local CSR build + gather (no float atomics):
//   bin (8 dst-range buckets, ballot-compacted, fused degree) ->
//   dis -> scan -> fine CSR fill (per-bucket, L2-local) -> h=xW^T -> gather
// N=100000, D=64, E=3200000

#define NBKT 8

// Pass over edges: count degree + partition into 8 dst-range buckets with
// wave-compacted contiguous appends (packed record: src<<14 | dst_local).
__global__ void bin_k(const int* __restrict__ ei, int* __restrict__ deg,
                      int* __restrict__ bcur, unsigned* __restrict__ pairs,
                      int E, int nper, int bcap) {
    int lane = threadIdx.x & 63;
    long gw = ((long)blockIdx.x * blockDim.x + threadIdx.x) >> 6;
    long nw = ((long)gridDim.x * blockDim.x) >> 6;
    for (long base = gw * 64; base < E; base += nw * 64) {
        long e = base + lane;
        bool valid = e < E;
        int s = 0, d = 0, bkt = NBKT;   // NBKT = no bucket (invalid lane)
        if (valid) {
            s = ei[e];
            d = ei[E + e];
            atomicAdd(&deg[d], 1);
            bkt = d / nper;
        }
#pragma unroll
        for (int k = 0; k < NBKT; ++k) {
            unsigned long long mask = __ballot(bkt == k);
            if (mask) {
                int cnt = __popcll(mask);
                int leader = (int)__ffsll((long long)mask) - 1;
                int pos0 = 0;
                if (lane == leader) pos0 = atomicAdd(&bcur[k], cnt);
                pos0 = __shfl(pos0, leader, 64);
                if (bkt == k) {
                    int idx = pos0 + (int)__popcll(mask & ((1ull << lane) - 1));
                    pairs[(size_t)k * bcap + idx] =
                        ((unsigned)s << 14) | (unsigned)(d - k * nper);
                }
            }
        }
    }
}

__global__ void dis_k(const int* __restrict__ deg, float* __restrict__ dis, int N) {
    int n = blockIdx.x * blockDim.x + threadIdx.x;
    if (n < N) dis[n] = rsqrtf((float)(deg[n] + 1));  // +1 self-loop
}

// --- 3-pass exclusive scan of deg[0..N) -> rowptr ---
__global__ void scan1_k(const int* __restrict__ deg, int* __restrict__ rowptr,
                        int* __restrict__ bsum, int N) {
    __shared__ int tmp[256];
    int t = threadIdx.x;
    int g = blockIdx.x * 256 + t;
    int v = (g < N) ? deg[g] : 0;
    tmp[t] = v;
    __syncthreads();
#pragma unroll
    for (int off = 1; off < 256; off <<= 1) {
        int add = (t >= off) ? tmp[t - off] : 0;
        __syncthreads();
        tmp[t] += add;
        __syncthreads();
    }
    if (g < N) rowptr[g] = tmp[t] - v;
    if (t == 255) bsum[blockIdx.x] = tmp[255];
}

__global__ void scan2_k(int* __restrict__ bsum, int nb, int* __restrict__ rowptr,
                        int N, int E) {
    __shared__ int tmp[512];
    int t = threadIdx.x;
    int v = (t < nb) ? bsum[t] : 0;
    tmp[t] = v;
    __syncthreads();
#pragma unroll
    for (int off = 1; off < 512; off <<= 1) {
        int add = (t >= off) ? tmp[t - off] : 0;
        __syncthreads();
        tmp[t] += add;
        __syncthreads();
    }
    if (t < nb) bsum[t] = tmp[t] - v;
    if (t == 0) rowptr[N] = E;
}

__global__ void scan3_k(int* __restrict__ rowptr, int* __restrict__ cursor,
                        const int* __restrict__ bsum, int N) {
    int g = blockIdx.x * 256 + threadIdx.x;
    if (g < N) {
        int r = rowptr[g] + bsum[blockIdx.x];
        rowptr[g] = r;
        cursor[g] = r;
    }
}

// Fine CSR fill: blocks with blockIdx%8==k handle bucket k (dst range of
// 12500 nodes). ent segment (1.6MB) + cursors (50KB) stay in that XCD's L2
// (blockIdx%8 -> XCD round-robin heuristic), so scattered 4B writes coalesce
// into full-line writebacks.
__global__ void fine_k(const unsigned* __restrict__ pairs, const int* __restrict__ bcnt,
                       int* __restrict__ cursor, int* __restrict__ ent,
                       int nper, int bcap) {
    int myb = blockIdx.x & 7;
    int cnt = bcnt[myb];
    const unsigned* p = pairs + (size_t)myb * bcap;
    int base_node = myb * nper;
    int i = (int)(blockIdx.x >> 3) * blockDim.x + threadIdx.x;
    int stride = (int)(gridDim.x >> 3) * blockDim.x;
    for (; i < cnt; i += stride) {
        unsigned v = p[i];
        int src = (int)(v >> 14);
        int d = base_node + (int)(v & 16383u);
        int pos = atomicAdd(&cursor[d], 1);
        ent[pos] = src;
    }
}

// h = x @ W^T : 4 rows/block, W staged in LDS padded [64][65].
__global__ void transform_k(const float* __restrict__ x, const float* __restrict__ W,
                            float* __restrict__ h, int N) {
    __shared__ float Wl[64][65];
    __shared__ float xl[4][64];
    int t = threadIdx.x;
    for (int i = t; i < 64 * 64; i += 256) Wl[i >> 6][i & 63] = W[i];
    int r = t >> 6;
    int c = t & 63;
    int row = blockIdx.x * 4 + r;
    xl[r][c] = (row < N) ? x[row * 64 + c] : 0.0f;
    __syncthreads();
    float acc = 0.0f;
#pragma unroll
    for (int k = 0; k < 64; ++k) acc += xl[r][k] * Wl[c][k];
    if (row < N) h[row * 64 + c] = acc;
}

// One wave per node: registers accumulate, single coalesced write. No atomics.
__global__ void gather_k(const int* __restrict__ rowptr, const int* __restrict__ ent,
                         const float* __restrict__ dis, const float* __restrict__ h,
                         const float* __restrict__ b, float* __restrict__ out, int N) {
    int lane = threadIdx.x & 63;
    int wpb = blockDim.x >> 6;
    int n = blockIdx.x * wpb + (threadIdx.x >> 6);
    if (n >= N) return;
    float dn = dis[n];
    float acc = h[n * 64 + lane] * dn * dn + b[lane];  // self-loop + bias
    int beg = rowptr[n];
    int end = rowptr[n + 1];
    for (int i = beg; i < end; i += 64) {
        int m = end - i;
        if (m > 64) m = 64;
        int src = 0;
        float nrm = 0.0f;
        if (lane < m) {
            src = ent[i + lane];
            nrm = dis[src] * dn;
        }
        for (int j = 0; j < m; ++j) {
            int s = __shfl(src, j, 64);
            float w = __shfl(nrm, j, 64);
            acc += h[s * 64 + lane] * w;
        }
    }
    out[n * 64 + lane] = acc;
}

extern "C" void kernel_launch(void* const* d_in, const int* in_sizes, int n_in,
                              void* d_out, int out_size, void* d_ws, size_t ws_size,
                              hipStream_t stream) {
    const float* x  = (const float*)d_in[0];
    const int*   ei = (const int*)d_in[1];
    const float* W  = (const float*)d_in[2];
    const float* b  = (const float*)d_in[3];
    float* out = (float*)d_out;

    int N = in_sizes[0] / 64;
    int E = in_sizes[1] / 2;
    int nb = (N + 255) / 256;
    int nper = (N + NBKT - 1) / NBKT;           // 12500
    int bcap = E / NBKT + 40000;                // mean 400K + 67 sigma slack

    char* ws = (char*)d_ws;
    size_t off = 0;
    auto alloc = [&](size_t bytes) { char* p = ws + off; off += (bytes + 255) & ~(size_t)255; return p; };
    int*      deg    = (int*)alloc((size_t)N * 4);
    float*    dis    = (float*)alloc((size_t)N * 4);
    int*      rowptr = (int*)alloc((size_t)(N + 1) * 4);
    int*      cursor = (int*)alloc((size_t)N * 4);
    int*      bsum   = (int*)alloc(512 * 4);
    int*      bcur   = (int*)alloc(NBKT * 4);
    unsigned* pairs  = (unsigned*)alloc((size_t)NBKT * bcap * 4);
    int*      ent    = (int*)alloc((size_t)E * 4);
    float*    h      = (float*)alloc((size_t)N * 64 * 4);

    hipMemsetAsync(deg, 0, (size_t)N * 4, stream);
    hipMemsetAsync(bcur, 0, NBKT * 4, stream);
    bin_k<<<2048, 256, 0, stream>>>(ei, deg, bcur, pairs, E, nper, bcap);
    dis_k<<<(N + 255) / 256, 256, 0, stream>>>(deg, dis, N);
    scan1_k<<<nb, 256, 0, stream>>>(deg, rowptr, bsum, N);
    scan2_k<<<1, 512, 0, stream>>>(bsum, nb, rowptr, N, E);
    scan3_k<<<nb, 256, 0, stream>>>(rowptr, cursor, bsum, N);
    fine_k<<<2048, 256, 0, stream>>>(pairs, bcur, cursor, ent, nper, bcap);
    transform_k<<<(N + 3) / 4, 256, 0, stream>>>(x, W, h, N);
    gather_k<<<(N + 3) / 4, 256, 0, stream>>>(rowptr, ent, dis, h, b, out, N);
}

// Round 4
// 516.036 us; speedup vs baseline: 9.5658x; 9.5658x over previous
//
#include <hip/hip_runtime.h>

// GCNConv via CSR-gather, CSR fill made L2-local by dst-range block groups:
//   degree -> dis -> scan -> fill8 (blockIdx&7 == dst-range == XCD) ->
//   h = x@W^T -> gather (one wave per node, no float atomics)
// N=100000, D=64, E=3200000

__global__ void degree_k(const int* __restrict__ ei, int* __restrict__ deg, int E) {
    int i = blockIdx.x * blockDim.x + threadIdx.x;
    int stride = gridDim.x * blockDim.x;
    for (int e = i; e < E; e += stride) {
        atomicAdd(&deg[ei[E + e]], 1);   // dst row
    }
}

__global__ void dis_k(const int* __restrict__ deg, float* __restrict__ dis, int N) {
    int n = blockIdx.x * blockDim.x + threadIdx.x;
    if (n < N) dis[n] = rsqrtf((float)(deg[n] + 1));  // +1 self-loop
}

// --- 3-pass exclusive scan of deg[0..N) -> rowptr ---
__global__ void scan1_k(const int* __restrict__ deg, int* __restrict__ rowptr,
                        int* __restrict__ bsum, int N) {
    __shared__ int tmp[256];
    int t = threadIdx.x;
    int g = blockIdx.x * 256 + t;
    int v = (g < N) ? deg[g] : 0;
    tmp[t] = v;
    __syncthreads();
#pragma unroll
    for (int off = 1; off < 256; off <<= 1) {
        int add = (t >= off) ? tmp[t - off] : 0;
        __syncthreads();
        tmp[t] += add;
        __syncthreads();
    }
    if (g < N) rowptr[g] = tmp[t] - v;
    if (t == 255) bsum[blockIdx.x] = tmp[255];
}

__global__ void scan2_k(int* __restrict__ bsum, int nb, int* __restrict__ rowptr,
                        int N, int E) {
    __shared__ int tmp[512];
    int t = threadIdx.x;
    int v = (t < nb) ? bsum[t] : 0;
    tmp[t] = v;
    __syncthreads();
#pragma unroll
    for (int off = 1; off < 512; off <<= 1) {
        int add = (t >= off) ? tmp[t - off] : 0;
        __syncthreads();
        tmp[t] += add;
        __syncthreads();
    }
    if (t < nb) bsum[t] = tmp[t] - v;
    if (t == 0) rowptr[N] = E;
}

__global__ void scan3_k(int* __restrict__ rowptr, int* __restrict__ cursor,
                        const int* __restrict__ bsum, int N) {
    int g = blockIdx.x * 256 + threadIdx.x;
    if (g < N) {
        int r = rowptr[g] + bsum[blockIdx.x];
        rowptr[g] = r;
        cursor[g] = r;
    }
}

// CSR fill, L2-local: block-group (blockIdx&7) -> XCD under round-robin
// dispatch; each group handles only dst in its 12500-node range, so its
// cursor slice (50KB) + ent slice (~1.6MB) stay in one XCD's 4MB L2 and
// scattered 4B stores become full-line writebacks. Edge list re-read 8x
// but L3-resident (25.6MB << 256MB).
__global__ void fill8_k(const int* __restrict__ ei, int* __restrict__ cursor,
                        int* __restrict__ ent, int E, int nper) {
    int grp = blockIdx.x & 7;
    int lo = grp * nper;
    int hi = lo + nper;
    int i = (int)(blockIdx.x >> 3) * blockDim.x + threadIdx.x;
    int stride = (int)(gridDim.x >> 3) * blockDim.x;
    for (int e = i; e < E; e += stride) {
        int d = ei[E + e];
        int s = ei[e];
        if (d >= lo && d < hi) {
            int pos = atomicAdd(&cursor[d], 1);
            ent[pos] = s;
        }
    }
}

// h = x @ W^T : 4 rows/block, W staged in LDS padded [64][65].
__global__ void transform_k(const float* __restrict__ x, const float* __restrict__ W,
                            float* __restrict__ h, int N) {
    __shared__ float Wl[64][65];
    __shared__ float xl[4][64];
    int t = threadIdx.x;
    for (int i = t; i < 64 * 64; i += 256) Wl[i >> 6][i & 63] = W[i];
    int r = t >> 6;
    int c = t & 63;
    int row = blockIdx.x * 4 + r;
    xl[r][c] = (row < N) ? x[row * 64 + c] : 0.0f;
    __syncthreads();
    float acc = 0.0f;
#pragma unroll
    for (int k = 0; k < 64; ++k) acc += xl[r][k] * Wl[c][k];
    if (row < N) h[row * 64 + c] = acc;
}

// One wave per node: registers accumulate, single coalesced write. No atomics.
__global__ void gather_k(const int* __restrict__ rowptr, const int* __restrict__ ent,
                         const float* __restrict__ dis, const float* __restrict__ h,
                         const float* __restrict__ b, float* __restrict__ out, int N) {
    int lane = threadIdx.x & 63;
    int wpb = blockDim.x >> 6;
    int n = blockIdx.x * wpb + (threadIdx.x >> 6);
    if (n >= N) return;
    float dn = dis[n];
    float acc = h[n * 64 + lane] * dn * dn + b[lane];  // self-loop + bias
    int beg = rowptr[n];
    int end = rowptr[n + 1];
    for (int i = beg; i < end; i += 64) {
        int m = end - i;
        if (m > 64) m = 64;
        int src = 0;
        float nrm = 0.0f;
        if (lane < m) {
            src = ent[i + lane];
            nrm = dis[src] * dn;
        }
        for (int j = 0; j < m; ++j) {
            int s = __shfl(src, j, 64);
            float w = __shfl(nrm, j, 64);
            acc += h[s * 64 + lane] * w;
        }
    }
    out[n * 64 + lane] = acc;
}

extern "C" void kernel_launch(void* const* d_in, const int* in_sizes, int n_in,
                              void* d_out, int out_size, void* d_ws, size_t ws_size,
                              hipStream_t stream) {
    const float* x  = (const float*)d_in[0];
    const int*   ei = (const int*)d_in[1];
    const float* W  = (const float*)d_in[2];
    const float* b  = (const float*)d_in[3];
    float* out = (float*)d_out;

    int N = in_sizes[0] / 64;
    int E = in_sizes[1] / 2;
    int nb = (N + 255) / 256;
    int nper = (N + 7) / 8;   // 12500 nodes per dst-range group

    char* ws = (char*)d_ws;
    size_t off = 0;
    auto alloc = [&](size_t bytes) { char* p = ws + off; off += (bytes + 255) & ~(size_t)255; return p; };
    int*   deg    = (int*)alloc((size_t)N * 4);
    float* dis    = (float*)alloc((size_t)N * 4);
    int*   rowptr = (int*)alloc((size_t)(N + 1) * 4);
    int*   cursor = (int*)alloc((size_t)N * 4);
    int*   bsum   = (int*)alloc(512 * 4);
    int*   ent    = (int*)alloc((size_t)E * 4);
    float* h      = (float*)alloc((size_t)N * 64 * 4);

    hipMemsetAsync(deg, 0, (size_t)N * 4, stream);
    degree_k<<<2048, 256, 0, stream>>>(ei, deg, E);
    dis_k<<<(N + 255) / 256, 256, 0, stream>>>(deg, dis, N);
    scan1_k<<<nb, 256, 0, stream>>>(deg, rowptr, bsum, N);
    scan2_k<<<1, 512, 0, stream>>>(bsum, nb, rowptr, N, E);
    scan3_k<<<nb, 256, 0, stream>>>(rowptr, cursor, bsum, N);
    fill8_k<<<2048, 256, 0, stream>>>(ei, cursor, ent, E, nper);
    transform_k<<<(N + 3) / 4, 256, 0, stream>>>(x, W, h, N);
    gather_k<<<(N + 3) / 4, 256, 0, stream>>>(rowptr, ent, dis, h, b, out, N);
}

// Round 5
// 505.122 us; speedup vs baseline: 9.7724x; 1.0216x over previous
//
#include <hip/hip_runtime.h>
#include <hip/hip_fp16.h>

// GCNConv via CSR-gather with fp16 h (halves random-gather traffic):
//   degree -> scan(+dis fused) -> fill8 (dst-range = XCD-local) ->
//   h = fp16(x@W^T) -> gather (one wave per node, f32 accum, no float atomics)
// N=100000, D=64, E=3200000

__global__ void degree_k(const int* __restrict__ ei, int* __restrict__ deg, int E) {
    int i = blockIdx.x * blockDim.x + threadIdx.x;
    int stride = gridDim.x * blockDim.x;
    for (int e = i; e < E; e += stride) {
        atomicAdd(&deg[ei[E + e]], 1);   // dst row
    }
}

// --- 3-pass exclusive scan of deg[0..N) -> rowptr; dis fused into pass 1 ---
__global__ void scan1_k(const int* __restrict__ deg, int* __restrict__ rowptr,
                        int* __restrict__ bsum, float* __restrict__ dis, int N) {
    __shared__ int tmp[256];
    int t = threadIdx.x;
    int g = blockIdx.x * 256 + t;
    int v = (g < N) ? deg[g] : 0;
    if (g < N) dis[g] = rsqrtf((float)(v + 1));   // +1 self-loop
    tmp[t] = v;
    __syncthreads();
#pragma unroll
    for (int off = 1; off < 256; off <<= 1) {
        int add = (t >= off) ? tmp[t - off] : 0;
        __syncthreads();
        tmp[t] += add;
        __syncthreads();
    }
    if (g < N) rowptr[g] = tmp[t] - v;
    if (t == 255) bsum[blockIdx.x] = tmp[255];
}

__global__ void scan2_k(int* __restrict__ bsum, int nb, int* __restrict__ rowptr,
                        int N, int E) {
    __shared__ int tmp[512];
    int t = threadIdx.x;
    int v = (t < nb) ? bsum[t] : 0;
    tmp[t] = v;
    __syncthreads();
#pragma unroll
    for (int off = 1; off < 512; off <<= 1) {
        int add = (t >= off) ? tmp[t - off] : 0;
        __syncthreads();
        tmp[t] += add;
        __syncthreads();
    }
    if (t < nb) bsum[t] = tmp[t] - v;
    if (t == 0) rowptr[N] = E;
}

__global__ void scan3_k(int* __restrict__ rowptr, int* __restrict__ cursor,
                        const int* __restrict__ bsum, int N) {
    int g = blockIdx.x * 256 + threadIdx.x;
    if (g < N) {
        int r = rowptr[g] + bsum[blockIdx.x];
        rowptr[g] = r;
        cursor[g] = r;
    }
}

// CSR fill, L2-local: block-group (blockIdx&7) -> XCD; each group handles
// only dst in its 12500-node range so cursor slice + ent slice stay in one
// XCD's L2. dst row streamed; src loaded lazily only on range match.
__global__ void fill8_k(const int* __restrict__ ei, int* __restrict__ cursor,
                        int* __restrict__ ent, int E, int nper) {
    int grp = blockIdx.x & 7;
    int lo = grp * nper;
    int hi = lo + nper;
    int i = (int)(blockIdx.x >> 3) * blockDim.x + threadIdx.x;
    int stride = (int)(gridDim.x >> 3) * blockDim.x;
    for (int e = i; e < E; e += stride) {
        int d = ei[E + e];
        if (d >= lo && d < hi) {
            int s = ei[e];
            int pos = atomicAdd(&cursor[d], 1);
            ent[pos] = s;
        }
    }
}

// h = fp16(x @ W^T) : 4 rows/block, W staged in LDS padded [64][65].
__global__ void transform_k(const float* __restrict__ x, const float* __restrict__ W,
                            __half* __restrict__ h, int N) {
    __shared__ float Wl[64][65];
    __shared__ float xl[4][64];
    int t = threadIdx.x;
    for (int i = t; i < 64 * 64; i += 256) Wl[i >> 6][i & 63] = W[i];
    int r = t >> 6;
    int c = t & 63;
    int row = blockIdx.x * 4 + r;
    xl[r][c] = (row < N) ? x[row * 64 + c] : 0.0f;
    __syncthreads();
    float acc = 0.0f;
#pragma unroll
    for (int k = 0; k < 64; ++k) acc += xl[r][k] * Wl[c][k];
    if (row < N) h[row * 64 + c] = __float2half(acc);
}

// One wave per node: fp16 row gathers (128B/row), f32 accumulate, single
// coalesced write. No atomics.
__global__ void gather_k(const int* __restrict__ rowptr, const int* __restrict__ ent,
                         const float* __restrict__ dis, const __half* __restrict__ h,
                         const float* __restrict__ b, float* __restrict__ out, int N) {
    int lane = threadIdx.x & 63;
    int wpb = blockDim.x >> 6;
    int n = blockIdx.x * wpb + (threadIdx.x >> 6);
    if (n >= N) return;
    float dn = dis[n];
    float acc = __half2float(h[(long)n * 64 + lane]) * dn * dn + b[lane];  // self-loop+bias
    int beg = rowptr[n];
    int end = rowptr[n + 1];
    for (int i = beg; i < end; i += 64) {
        int m = end - i;
        if (m > 64) m = 64;
        int src = 0;
        float nrm = 0.0f;
        if (lane < m) {
            src = ent[i + lane];            // coalesced chunk of edge sources
            nrm = dis[src] * dn;            // random 4B reads, L2-resident (400KB)
        }
        for (int j = 0; j < m; ++j) {
            int s = __shfl(src, j, 64);
            float w = __shfl(nrm, j, 64);
            acc += __half2float(h[(long)s * 64 + lane]) * w;  // 128B row gather
        }
    }
    out[(long)n * 64 + lane] = acc;
}

extern "C" void kernel_launch(void* const* d_in, const int* in_sizes, int n_in,
                              void* d_out, int out_size, void* d_ws, size_t ws_size,
                              hipStream_t stream) {
    const float* x  = (const float*)d_in[0];
    const int*   ei = (const int*)d_in[1];
    const float* W  = (const float*)d_in[2];
    const float* b  = (const float*)d_in[3];
    float* out = (float*)d_out;

    int N = in_sizes[0] / 64;
    int E = in_sizes[1] / 2;
    int nb = (N + 255) / 256;
    int nper = (N + 7) / 8;   // 12500 nodes per dst-range group

    char* ws = (char*)d_ws;
    size_t off = 0;
    auto alloc = [&](size_t bytes) { char* p = ws + off; off += (bytes + 255) & ~(size_t)255; return p; };
    int*    deg    = (int*)alloc((size_t)N * 4);
    float*  dis    = (float*)alloc((size_t)N * 4);
    int*    rowptr = (int*)alloc((size_t)(N + 1) * 4);
    int*    cursor = (int*)alloc((size_t)N * 4);
    int*    bsum   = (int*)alloc(512 * 4);
    int*    ent    = (int*)alloc((size_t)E * 4);
    __half* h      = (__half*)alloc((size_t)N * 64 * 2);

    hipMemsetAsync(deg, 0, (size_t)N * 4, stream);
    degree_k<<<2048, 256, 0, stream>>>(ei, deg, E);
    scan1_k<<<nb, 256, 0, stream>>>(deg, rowptr, bsum, dis, N);
    scan2_k<<<1, 512, 0, stream>>>(bsum, nb, rowptr, N, E);
    scan3_k<<<nb, 256, 0, stream>>>(rowptr, cursor, bsum, N);
    fill8_k<<<2048, 256, 0, stream>>>(ei, cursor, ent, E, nper);
    transform_k<<<(N + 3) / 4, 256, 0, stream>>>(x, W, h, N);
    gather_k<<<(N + 3) / 4, 256, 0, stream>>>(rowptr, ent, dis, h, b, out, N);
}

// Round 6
// 407.346 us; speedup vs baseline: 12.1181x; 1.2400x over previous
//
#include <hip/hip_runtime.h>
#include <hip/hip_fp16.h>

// GCNConv via CSR-gather, latency-hidden:
//   degree -> scan(+dis) -> fill8 (dst-range = XCD-local) ->
//   h' = fp16((x@W^T) * dis[row]) -> gather: out = dn*(h'[n] + sum h'[src]) + b
//   gather inner loop unrolled x8 (8 loads in flight per wave).
// N=100000, D=64, E=3200000

__global__ void degree_k(const int* __restrict__ ei, int* __restrict__ deg, int E) {
    int i = blockIdx.x * blockDim.x + threadIdx.x;
    int stride = gridDim.x * blockDim.x;
    for (int e = i; e < E; e += stride) {
        atomicAdd(&deg[ei[E + e]], 1);   // dst row
    }
}

// --- 3-pass exclusive scan of deg[0..N) -> rowptr; dis fused into pass 1 ---
__global__ void scan1_k(const int* __restrict__ deg, int* __restrict__ rowptr,
                        int* __restrict__ bsum, float* __restrict__ dis, int N) {
    __shared__ int tmp[256];
    int t = threadIdx.x;
    int g = blockIdx.x * 256 + t;
    int v = (g < N) ? deg[g] : 0;
    if (g < N) dis[g] = rsqrtf((float)(v + 1));   // +1 self-loop
    tmp[t] = v;
    __syncthreads();
#pragma unroll
    for (int off = 1; off < 256; off <<= 1) {
        int add = (t >= off) ? tmp[t - off] : 0;
        __syncthreads();
        tmp[t] += add;
        __syncthreads();
    }
    if (g < N) rowptr[g] = tmp[t] - v;
    if (t == 255) bsum[blockIdx.x] = tmp[255];
}

__global__ void scan2_k(int* __restrict__ bsum, int nb, int* __restrict__ rowptr,
                        int N, int E) {
    __shared__ int tmp[512];
    int t = threadIdx.x;
    int v = (t < nb) ? bsum[t] : 0;
    tmp[t] = v;
    __syncthreads();
#pragma unroll
    for (int off = 1; off < 512; off <<= 1) {
        int add = (t >= off) ? tmp[t - off] : 0;
        __syncthreads();
        tmp[t] += add;
        __syncthreads();
    }
    if (t < nb) bsum[t] = tmp[t] - v;
    if (t == 0) rowptr[N] = E;
}

__global__ void scan3_k(int* __restrict__ rowptr, int* __restrict__ cursor,
                        const int* __restrict__ bsum, int N) {
    int g = blockIdx.x * 256 + threadIdx.x;
    if (g < N) {
        int r = rowptr[g] + bsum[blockIdx.x];
        rowptr[g] = r;
        cursor[g] = r;
    }
}

// CSR fill, L2-local: block-group (blockIdx&7) -> XCD; each group handles
// only dst in its 12500-node range so its cursor + ent slices stay in one
// XCD's L2 and 4B scatters become full-line writebacks.
__global__ void fill8_k(const int* __restrict__ ei, int* __restrict__ cursor,
                        int* __restrict__ ent, int E, int nper) {
    int grp = blockIdx.x & 7;
    int lo = grp * nper;
    int hi = lo + nper;
    int i = (int)(blockIdx.x >> 3) * blockDim.x + threadIdx.x;
    int stride = (int)(gridDim.x >> 3) * blockDim.x;
    for (int e = i; e < E; e += stride) {
        int d = ei[E + e];
        if (d >= lo && d < hi) {
            int s = ei[e];
            int pos = atomicAdd(&cursor[d], 1);
            ent[pos] = s;
        }
    }
}

// h' = fp16((x @ W^T) * dis[row]) : 4 rows/block, W staged in LDS [64][65].
__global__ void transform_k(const float* __restrict__ x, const float* __restrict__ W,
                            const float* __restrict__ dis, __half* __restrict__ h, int N) {
    __shared__ float Wl[64][65];
    __shared__ float xl[4][64];
    int t = threadIdx.x;
    for (int i = t; i < 64 * 64; i += 256) Wl[i >> 6][i & 63] = W[i];
    int r = t >> 6;
    int c = t & 63;
    int row = blockIdx.x * 4 + r;
    xl[r][c] = (row < N) ? x[row * 64 + c] : 0.0f;
    __syncthreads();
    float acc = 0.0f;
#pragma unroll
    for (int k = 0; k < 64; ++k) acc += xl[r][k] * Wl[c][k];
    if (row < N) h[row * 64 + c] = __float2half(acc * dis[row]);
}

// One wave per node. Inner loop unrolled x8: 8 independent shfl + 8
// independent 2B loads in flight -> hides L3 gather latency.
__global__ void gather_k(const int* __restrict__ rowptr, const int* __restrict__ ent,
                         const float* __restrict__ dis, const __half* __restrict__ h,
                         const float* __restrict__ b, float* __restrict__ out, int N) {
    int lane = threadIdx.x & 63;
    int n = blockIdx.x * (blockDim.x >> 6) + (threadIdx.x >> 6);
    if (n >= N) return;
    float acc = __half2float(h[(long)n * 64 + lane]);   // self-loop term (h' = h*dis)
    int beg = rowptr[n];
    int end = rowptr[n + 1];
    for (int i = beg; i < end; i += 64) {
        int m = end - i;
        if (m > 64) m = 64;
        int src = (lane < m) ? ent[i + lane] : 0;
        int j = 0;
        for (; j + 8 <= m; j += 8) {
            int s0 = __shfl(src, j + 0, 64);
            int s1 = __shfl(src, j + 1, 64);
            int s2 = __shfl(src, j + 2, 64);
            int s3 = __shfl(src, j + 3, 64);
            int s4 = __shfl(src, j + 4, 64);
            int s5 = __shfl(src, j + 5, 64);
            int s6 = __shfl(src, j + 6, 64);
            int s7 = __shfl(src, j + 7, 64);
            float v0 = __half2float(h[(long)s0 * 64 + lane]);
            float v1 = __half2float(h[(long)s1 * 64 + lane]);
            float v2 = __half2float(h[(long)s2 * 64 + lane]);
            float v3 = __half2float(h[(long)s3 * 64 + lane]);
            float v4 = __half2float(h[(long)s4 * 64 + lane]);
            float v5 = __half2float(h[(long)s5 * 64 + lane]);
            float v6 = __half2float(h[(long)s6 * 64 + lane]);
            float v7 = __half2float(h[(long)s7 * 64 + lane]);
            acc += ((v0 + v1) + (v2 + v3)) + ((v4 + v5) + (v6 + v7));
        }
        for (; j < m; ++j) {
            int s = __shfl(src, j, 64);
            acc += __half2float(h[(long)s * 64 + lane]);
        }
    }
    out[(long)n * 64 + lane] = acc * dis[n] + b[lane];
}

extern "C" void kernel_launch(void* const* d_in, const int* in_sizes, int n_in,
                              void* d_out, int out_size, void* d_ws, size_t ws_size,
                              hipStream_t stream) {
    const float* x  = (const float*)d_in[0];
    const int*   ei = (const int*)d_in[1];
    const float* W  = (const float*)d_in[2];
    const float* b  = (const float*)d_in[3];
    float* out = (float*)d_out;

    int N = in_sizes[0] / 64;
    int E = in_sizes[1] / 2;
    int nb = (N + 255) / 256;
    int nper = (N + 7) / 8;   // 12500 nodes per dst-range group

    char* ws = (char*)d_ws;
    size_t off = 0;
    auto alloc = [&](size_t bytes) { char* p = ws + off; off += (bytes + 255) & ~(size_t)255; return p; };
    int*    deg    = (int*)alloc((size_t)N * 4);
    float*  dis    = (float*)alloc((size_t)N * 4);
    int*    rowptr = (int*)alloc((size_t)(N + 1) * 4);
    int*    cursor = (int*)alloc((size_t)N * 4);
    int*    bsum   = (int*)alloc(512 * 4);
    int*    ent    = (int*)alloc((size_t)E * 4);
    __half* h      = (__half*)alloc((size_t)N * 64 * 2);

    hipMemsetAsync(deg, 0, (size_t)N * 4, stream);
    degree_k<<<2048, 256, 0, stream>>>(ei, deg, E);
    scan1_k<<<nb, 256, 0, stream>>>(deg, rowptr, bsum, dis, N);
    scan2_k<<<1, 512, 0, stream>>>(bsum, nb, rowptr, N, E);
    scan3_k<<<nb, 256, 0, stream>>>(rowptr, cursor, bsum, N);
    fill8_k<<<2048, 256, 0, stream>>>(ei, cursor, ent, E, nper);
    transform_k<<<(N + 3) / 4, 256, 0, stream>>>(x, W, dis, h, N);
    gather_k<<<(N + 3) / 4, 256, 0, stream>>>(rowptr, ent, dis, h, b, out, N);
}